// Round 6
// baseline (7784.321 us; speedup 1.0000x reference)
//
#include <hip/hip_runtime.h>

// VectorQuantizer: N=262144 rows of D=64 fp32, K=1024 codebook rows.
// out = [x_quantized (N*D f32) | embed_inds (N, written as f32)]
//
// Bit-exact replication of np reference fp32 semantics (verified R4):
//   score(row,k) = fmaf(-2, seq-FMA-dot, fadd(xnorm, enorm)); argmin = first-min.
//
// R6 structure (fetch-bound fix): TRANSPOSED. Each lane holds 2 codebook rows
// in 128 VGPRs (8 waves x 64 lanes x 2 = K=1024). x rows stream through LDS
// tiles (double-buffered, reg-staged prefetch). Per row per wave: 16 broadcast
// ds_read_b128 feed 128 FMA instructions (vs 16 fetches per 64 FMAs in R4/R5).
// Argmin via shfl_xor butterfly + cross-wave merge, exact first-min tie-break.

static constexpr int D_DIM = 64;
static constexpr int K_CB  = 1024;
static constexpr int TPB   = 512;            // 8 waves
static constexpr int TILE  = 128;            // x rows per LDS tile (32 KB)
static constexpr int RPB   = 1024;           // rows per block
static constexpr int NT    = RPB / TILE;     // 8 tiles

// numpy pairwise sum, n=64 path: 8 accumulators, sequential adds, fixed tree.
__device__ __forceinline__ float np_sum64_sq(const float* v) {
    float r[8];
#pragma unroll
    for (int j = 0; j < 8; ++j) r[j] = __fmul_rn(v[j], v[j]);
#pragma unroll
    for (int i = 8; i < 64; i += 8)
#pragma unroll
        for (int j = 0; j < 8; ++j) r[j] = __fadd_rn(r[j], __fmul_rn(v[i + j], v[i + j]));
    float t01 = __fadd_rn(r[0], r[1]), t23 = __fadd_rn(r[2], r[3]);
    float t45 = __fadd_rn(r[4], r[5]), t67 = __fadd_rn(r[6], r[7]);
    return __fadd_rn(__fadd_rn(t01, t23), __fadd_rn(t45, t67));
}

__global__ void __launch_bounds__(TPB, 2) vq_kernel(
        const float* __restrict__ x, const float* __restrict__ cb,
        float* __restrict__ out_q, float* __restrict__ out_idx) {
    __shared__ float xt[2][TILE * D_DIM];   // 64 KB, double-buffered x tiles
    __shared__ float xnorm[RPB];            // 4 KB
    __shared__ float ps[8][TILE];           // per-wave partial scores
    __shared__ int   pk[8][TILE];           // per-wave partial indices
    __shared__ int   bks[TILE];

    const int tid  = threadIdx.x;
    const int lane = tid & 63;
    const int w    = tid >> 6;
    const size_t brow0 = (size_t)blockIdx.x * RPB;

    // ---- phase 0a: x_norms for all 1024 block rows (numpy pairwise order) ----
    {
        float tmp[D_DIM];
#pragma unroll
        for (int rr = 0; rr < RPB / TPB; ++rr) {
            const int r = tid + rr * TPB;
            const float4* g = reinterpret_cast<const float4*>(x + (brow0 + r) * D_DIM);
#pragma unroll
            for (int c = 0; c < 16; ++c) {
                float4 v = g[c];
                tmp[4*c+0] = v.x; tmp[4*c+1] = v.y; tmp[4*c+2] = v.z; tmp[4*c+3] = v.w;
            }
            xnorm[r] = np_sum64_sq(tmp);
        }
    }

    // ---- phase 0b: stage tile 0 (coalesced) ----
    {
        const float4* g = reinterpret_cast<const float4*>(x + brow0 * D_DIM);
        float4* dst = reinterpret_cast<float4*>(xt[0]);
#pragma unroll
        for (int i = 0; i < 4; ++i) dst[tid + TPB * i] = g[tid + TPB * i];
    }

    // ---- phase 0c: my 2 codebook rows -> 128 VGPRs; register e-norms ----
    float cbr0[D_DIM], cbr1[D_DIM];
    const int k0 = w * 128 + lane;
    const int k1 = k0 + 64;
    {
        const float4* g0 = reinterpret_cast<const float4*>(cb + (size_t)k0 * D_DIM);
        const float4* g1 = reinterpret_cast<const float4*>(cb + (size_t)k1 * D_DIM);
#pragma unroll
        for (int c = 0; c < 16; ++c) {
            float4 a = g0[c];
            cbr0[4*c+0] = a.x; cbr0[4*c+1] = a.y; cbr0[4*c+2] = a.z; cbr0[4*c+3] = a.w;
            float4 b = g1[c];
            cbr1[4*c+0] = b.x; cbr1[4*c+1] = b.y; cbr1[4*c+2] = b.z; cbr1[4*c+3] = b.w;
        }
    }
    const float en0 = np_sum64_sq(cbr0);
    const float en1 = np_sum64_sq(cbr1);

    __syncthreads();

    for (int t = 0; t < NT; ++t) {
        const int A = t & 1;
        const float* xtc = xt[A];

        // Prefetch next tile into registers now; LDS-write after main loop (T14).
        float4 pre[4];
        const bool hasNext = (t + 1 < NT);
        if (hasNext) {
            const float4* g = reinterpret_cast<const float4*>(
                x + (brow0 + (size_t)(t + 1) * TILE) * D_DIM);
#pragma unroll
            for (int i = 0; i < 4; ++i) pre[i] = g[tid + TPB * i];
        }

        // ---- main: 128 rows, batched by 4 for reduce-latency overlap ----
        for (int rb = 0; rb < TILE; rb += 4) {
            float ss[4]; int kk[4];
#pragma unroll
            for (int u = 0; u < 4; ++u) {
                const int r = rb + u;
                const float xn = xnorm[t * TILE + r];
                float d0 = 0.f, d1 = 0.f;
#pragma unroll
                for (int c = 0; c < 16; ++c) {
                    const float4 xv = *reinterpret_cast<const float4*>(&xtc[r * D_DIM + 4 * c]);
                    d0 = __fmaf_rn(xv.x, cbr0[4*c+0], d0);
                    d1 = __fmaf_rn(xv.x, cbr1[4*c+0], d1);
                    d0 = __fmaf_rn(xv.y, cbr0[4*c+1], d0);
                    d1 = __fmaf_rn(xv.y, cbr1[4*c+1], d1);
                    d0 = __fmaf_rn(xv.z, cbr0[4*c+2], d0);
                    d1 = __fmaf_rn(xv.z, cbr1[4*c+2], d1);
                    d0 = __fmaf_rn(xv.w, cbr0[4*c+3], d0);
                    d1 = __fmaf_rn(xv.w, cbr1[4*c+3], d1);
                }
                const float s0 = __fmaf_rn(-2.f, d0, __fadd_rn(xn, en0));
                const float s1 = __fmaf_rn(-2.f, d1, __fadd_rn(xn, en1));
                const bool take1 = (s1 < s0);       // tie -> s0 (k0 < k1)
                ss[u] = take1 ? s1 : s0;
                kk[u] = take1 ? k1 : k0;
            }
            // 4 interleaved butterfly reduces; exact first-min (index tie-break).
#pragma unroll
            for (int m = 1; m < 64; m <<= 1) {
#pragma unroll
                for (int u = 0; u < 4; ++u) {
                    const float s2 = __shfl_xor(ss[u], m);
                    const int   q2 = __shfl_xor(kk[u], m);
                    if (s2 < ss[u] || (s2 == ss[u] && q2 < kk[u])) { ss[u] = s2; kk[u] = q2; }
                }
            }
            if (lane == 0) {
#pragma unroll
                for (int u = 0; u < 4; ++u) { ps[w][rb + u] = ss[u]; pk[w][rb + u] = kk[u]; }
            }
        }

        // Write prefetched tile into the other buffer (vmcnt waited here, not earlier).
        if (hasNext) {
            float4* dst = reinterpret_cast<float4*>(xt[1 - A]);
#pragma unroll
            for (int i = 0; i < 4; ++i) dst[tid + TPB * i] = pre[i];
        }
        __syncthreads();

        // ---- merge 8 wave-partials per row (ascending w = ascending k) ----
        if (tid < TILE) {
            float b = ps[0][tid]; int bk = pk[0][tid];
#pragma unroll
            for (int ww = 1; ww < 8; ++ww) {
                const float s2 = ps[ww][tid]; const int q2 = pk[ww][tid];
                if (s2 < b) { b = s2; bk = q2; }   // tie keeps lower w (lower k)
            }
            bks[tid] = bk;
            out_idx[brow0 + (size_t)t * TILE + tid] = (float)bk;
        }
        __syncthreads();

        // ---- coalesced gather-write of x_quantized for this tile ----
        {
            const float4* cbg = reinterpret_cast<const float4*>(cb);
            float4* oq = reinterpret_cast<float4*>(out_q + (brow0 + (size_t)t * TILE) * D_DIM);
#pragma unroll
            for (int j = 0; j < 4; ++j) {
                const int f = tid + TPB * j;        // 0..2047
                const int r = f >> 4, c = f & 15;
                oq[f] = cbg[(size_t)bks[r] * 16 + c];
            }
        }
        // No barrier needed: next tile's ps/pk writes come after merge consumed
        // them (all threads passed the post-merge barrier), bks only read here.
    }
}

extern "C" void kernel_launch(void* const* d_in, const int* in_sizes, int n_in,
                              void* d_out, int out_size, void* d_ws, size_t ws_size,
                              hipStream_t stream) {
    const float* x  = (const float*)d_in[0];
    const float* cb = (const float*)d_in[1];
    const int n_rows = in_sizes[0] / D_DIM;     // 262144

    float* out_q   = (float*)d_out;
    float* out_idx = out_q + (size_t)n_rows * D_DIM;

    vq_kernel<<<n_rows / RPB, TPB, 0, stream>>>(x, cb, out_q, out_idx);
}